// Round 8
// baseline (299.411 us; speedup 1.0000x reference)
//
#include <hip/hip_runtime.h>
#include <math.h>

// ---------------------------------------------------------------------------
// Only sample 0 of the batch affects the loss (features[0], cap[0]).
// ONE kernel, grid 108 x 512 (all co-resident, 1 block/CU):
//   bx 0       init: zero vacc/asum/flags/loss; poison U/H/feat (0xAA);
//              __syncthreads drains stores; release MAGIC.
//   bx 1..32   conv1+conv2+NetVLAD fused (4 conv2-output rows/block):
//              conv1+pool -> LDS tile (4ch x 10 x 258), conv2+relu+pool,
//              softmax, accumulate; MAGIC gate only before vacc/asum
//              atomics; tick vlad_done.
//   bx 33..40  FC: wait vlad_done==32; normalize vlad; 64 feat rows each;
//              agent-store feat.
//   bx 41..44  RNN: 128 rows/block, W_h slice in regs; DATA-AS-FLAG sync
//              (H/U/feat poisoned; sigmoid/dot outputs can't be 0xAA..):
//              feat poll 1 cell/thread, U poll w/ one-step prefetch (cg==0
//              only), H poll 1 cell/thread, double-buffered swizzled LDS,
//              single barrier per step.
//   bx 45..107 loss t: MAGIC gate; compute U[t] (agent stores); sentinel
//              poll H[t*512] w/ s_sleep backoff; row poll; y_t; sq-error.
// ---------------------------------------------------------------------------

#define POISON 0xAAAAAAAAu
#define MAGIC  0x13579BDFu

__device__ __forceinline__ float sigmoidf_(float x) {
  return 1.0f / (1.0f + __expf(-x));
}
__device__ __forceinline__ unsigned uld(const unsigned* p) {
  return __hip_atomic_load(p, __ATOMIC_RELAXED, __HIP_MEMORY_SCOPE_AGENT);
}
__device__ __forceinline__ float fld(const float* p) {
  return __hip_atomic_load(p, __ATOMIC_RELAXED, __HIP_MEMORY_SCOPE_AGENT);
}
__device__ __forceinline__ void fst(float* p, float v) {
  __hip_atomic_store(p, v, __ATOMIC_RELAXED, __HIP_MEMORY_SCOPE_AGENT);
}
__device__ __forceinline__ void ust(unsigned* p, unsigned v) {
  __hip_atomic_store(p, v, __ATOMIC_RELAXED, __HIP_MEMORY_SCOPE_AGENT);
}

__global__ __launch_bounds__(512, 1)
void k_all(const float* __restrict__ img,  const float* __restrict__ cap,
           const float* __restrict__ c1w,  const float* __restrict__ c1b,
           const float* __restrict__ c2w,  const float* __restrict__ c2b,
           const float* __restrict__ cent, const float* __restrict__ nvw,
           const float* __restrict__ nvb,  const float* __restrict__ fcw,
           const float* __restrict__ fcb,  const float* __restrict__ hidw,
           const float* __restrict__ hidb, const float* __restrict__ outw,
           const float* __restrict__ outb,
           float* __restrict__ vacc, float* __restrict__ asum,
           float* __restrict__ feat, float* __restrict__ U,
           float* __restrict__ H,
           unsigned* __restrict__ flags, float* __restrict__ loss) {
  __shared__ __align__(16) float smem[23744];
  const int bx  = blockIdx.x;
  const int tid = threadIdx.x;
  unsigned* flag_magic = flags + 0;
  unsigned* vlad_done  = flags + 1;

  // ============================ init: bx 0 ============================
  if (bx == 0) {
    for (int i = tid; i < 1024; i += 512) fst(vacc + i, 0.f);
    if (tid < 64) fst(asum + tid, 0.f);
    if (tid == 0) { fst(loss, 0.f); ust(vlad_done, 0u); }
    unsigned* Uu = (unsigned*)U;
    unsigned* Hu = (unsigned*)H;
    unsigned* Fu = (unsigned*)feat;
    for (int i = tid; i < 63 * 512; i += 512) { ust(Uu + i, POISON); ust(Hu + i, POISON); }
    ust(Fu + tid, POISON);
    __syncthreads();                      // drain stores before MAGIC
    if (tid == 0) ust(flag_magic, MAGIC);
    return;
  }

  // ==================== conv1+conv2+NetVLAD: bx 1..32 ====================
  if (bx < 33) {
    const int vb = bx - 1;                 // 0..31: conv2-out rows [4vb,4vb+3]
    float* p1sh = smem;                    // 4*10*264 = 10560
    float* ps   = smem + 10560;            // 8320 (staging / red[512][16])
    float* xs   = smem + 18880;            // 2560
    float* wsh  = smem + 21440;            // 1024
    float* bsh  = smem + 22464;            // 64
    float* aS   = smem + 22528;            // 512
    float* cw2  = smem + 23040;            // 576
    float* cb2  = smem + 23616;            // 16
    float* cw1  = smem + 23632;            // 108
    float* cb1  = smem + 23740;            // 4
    for (int i = tid; i < 1024; i += 512) wsh[i] = nvw[i];
    if (tid < 64) bsh[tid] = nvb[tid];
    if (tid < 576) cw2[tid] = c2w[tid];
    if (tid >= 576 && tid < 592) cb2[tid - 576] = c2b[tid - 576];
    if (tid >= 592 && tid < 700) cw1[tid - 592] = c1w[tid - 592];
    if (tid >= 700 && tid < 704) cb1[tid - 700] = c1b[tid - 700];
    __syncthreads();

    // ---- conv1+relu+pool into LDS tile: p1 rows [8vb-1, 8vb+8], cols [-1,256]
    for (int f = tid; f < 10320; f += 512) {
      int c  = f / 2580;
      int r0 = f - c * 2580;
      int j  = r0 / 258;
      int xx = r0 - j * 258;
      int gy = 8 * vb - 1 + j;
      int gx = xx - 1;
      float val = 0.f;
      if ((unsigned)gy < 256u && (unsigned)gx < 256u) {
        float bb = cb1[c];
        float a00 = bb, a01 = bb, a10 = bb, a11 = bb;
        int y0 = 2 * gy - 1, x0 = 2 * gx - 1;
        #pragma unroll
        for (int ci = 0; ci < 3; ++ci) {
          float P[4][4];
          #pragma unroll
          for (int jj = 0; jj < 4; ++jj) {
            int y = y0 + jj;
            #pragma unroll
            for (int ii = 0; ii < 4; ++ii) {
              int x = x0 + ii;
              bool ok = ((unsigned)y < 512u) && ((unsigned)x < 512u);
              P[jj][ii] = ok ? img[ci * 262144 + y * 512 + x] : 0.0f;
            }
          }
          #pragma unroll
          for (int ky = 0; ky < 3; ++ky) {
            #pragma unroll
            for (int kx = 0; kx < 3; ++kx) {
              float wv = cw1[c * 27 + ci * 9 + ky * 3 + kx];
              a00 = fmaf(wv, P[ky][kx],         a00);
              a01 = fmaf(wv, P[ky][kx + 1],     a01);
              a10 = fmaf(wv, P[ky + 1][kx],     a10);
              a11 = fmaf(wv, P[ky + 1][kx + 1], a11);
            }
          }
        }
        val = 0.25f * (fmaxf(a00, 0.f) + fmaxf(a01, 0.f) +
                       fmaxf(a10, 0.f) + fmaxf(a11, 0.f));
      }
      p1sh[c * 2640 + j * 264 + xx] = val;
    }
    __syncthreads();

    // ---- conv2+relu+pool from LDS tile: 512 positions (4 rows x 128 cols)
    int ox = tid & 127;
    int oyl = tid >> 7;                    // 0..3
    float a[16][4];
    #pragma unroll
    for (int oc = 0; oc < 16; ++oc) {
      float bb = cb2[oc];
      a[oc][0] = bb; a[oc][1] = bb; a[oc][2] = bb; a[oc][3] = bb;
    }
    #pragma unroll
    for (int ci = 0; ci < 4; ++ci) {
      float P[4][4];
      #pragma unroll
      for (int jj = 0; jj < 4; ++jj) {
        #pragma unroll
        for (int ii = 0; ii < 4; ++ii)
          P[jj][ii] = p1sh[ci * 2640 + (2 * oyl + jj) * 264 + 2 * ox + ii];
      }
      #pragma unroll
      for (int oc = 0; oc < 16; ++oc) {
        #pragma unroll
        for (int ky = 0; ky < 3; ++ky) {
          #pragma unroll
          for (int kx = 0; kx < 3; ++kx) {
            float wv = cw2[oc * 36 + ci * 9 + ky * 3 + kx];
            a[oc][0] = fmaf(wv, P[ky][kx],         a[oc][0]);
            a[oc][1] = fmaf(wv, P[ky][kx + 1],     a[oc][1]);
            a[oc][2] = fmaf(wv, P[ky + 1][kx],     a[oc][2]);
            a[oc][3] = fmaf(wv, P[ky + 1][kx + 1], a[oc][3]);
          }
        }
      }
    }
    float x[16];
    #pragma unroll
    for (int oc = 0; oc < 16; ++oc)
      x[oc] = 0.25f * (fmaxf(a[oc][0], 0.f) + fmaxf(a[oc][1], 0.f) +
                       fmaxf(a[oc][2], 0.f) + fmaxf(a[oc][3], 0.f));

    // ---- NetVLAD softmax ----
    float p[64];
    float m = -1e30f;
    #pragma unroll
    for (int k = 0; k < 64; ++k) {
      float acc = bsh[k];
      #pragma unroll
      for (int c = 0; c < 16; ++c) acc = fmaf(wsh[k * 16 + c], x[c], acc);
      p[k] = acc;
      m = fmaxf(m, acc);
    }
    float s = 0.f;
    #pragma unroll
    for (int k = 0; k < 64; ++k) { p[k] = __expf(p[k] - m); s += p[k]; }
    float inv = 1.0f / s;
    #pragma unroll
    for (int k = 0; k < 64; ++k) p[k] *= inv;

    // ---- accumulate: 8 q-groups x 64 clusters; 4 staging passes of 128 ----
    int q = tid >> 6, k = tid & 63;
    float acc[16];
    #pragma unroll
    for (int c = 0; c < 16; ++c) acc[c] = 0.f;
    float accA = 0.f;
    for (int pass = 0; pass < 4; ++pass) {
      __syncthreads();
      if ((tid >> 7) == pass) {
        int tt = tid & 127;
        #pragma unroll
        for (int kk = 0; kk < 64; ++kk) ps[tt * 65 + kk] = p[kk];
        #pragma unroll
        for (int c = 0; c < 16; ++c) xs[tt * 20 + c] = x[c];
      }
      __syncthreads();
      #pragma unroll
      for (int j = 0; j < 16; ++j) {
        int tt = q * 16 + j;
        float pv = ps[tt * 65 + k];
        accA += pv;
        const float4* xv = (const float4*)(xs + tt * 20);
        #pragma unroll
        for (int c4 = 0; c4 < 4; ++c4) {
          float4 xx = xv[c4];
          acc[c4 * 4 + 0] = fmaf(pv, xx.x, acc[c4 * 4 + 0]);
          acc[c4 * 4 + 1] = fmaf(pv, xx.y, acc[c4 * 4 + 1]);
          acc[c4 * 4 + 2] = fmaf(pv, xx.z, acc[c4 * 4 + 2]);
          acc[c4 * 4 + 3] = fmaf(pv, xx.w, acc[c4 * 4 + 3]);
        }
      }
    }
    __syncthreads();
    float* red = ps;                       // reuse as [512][16]
    #pragma unroll
    for (int c = 0; c < 16; ++c) red[tid * 16 + c] = acc[c];
    aS[tid] = accA;
    __syncthreads();
    if (tid == 0) {                        // gate atomics on init done
      while (uld(flag_magic) != MAGIC) __builtin_amdgcn_s_sleep(2);
    }
    __syncthreads();
    if (q == 0) {
      float aa = 0.f;
      #pragma unroll
      for (int qq = 0; qq < 8; ++qq) aa += aS[qq * 64 + k];
      atomicAdd(&asum[k], aa);
    }
    int k2 = tid >> 3;                     // 0..63
    int c0 = (tid & 7) * 2;
    #pragma unroll
    for (int cc = 0; cc < 2; ++cc) {
      int c = c0 + cc;
      float vv = 0.f;
      #pragma unroll
      for (int qq = 0; qq < 8; ++qq) vv += red[(qq * 64 + k2) * 16 + c];
      atomicAdd(&vacc[k2 * 16 + c], vv);
    }
    __syncthreads();                       // drain atomics before tick
    if (tid == 0)
      __hip_atomic_fetch_add(vlad_done, 1u, __ATOMIC_RELAXED,
                             __HIP_MEMORY_SCOPE_AGENT);
    return;
  }

  // ============================ FC: bx 33..40 ============================
  if (bx < 41) {
    const int q = bx - 33;
    if (tid == 0) {
      while (uld(vlad_done) != 32u) __builtin_amdgcn_s_sleep(8);
    }
    __syncthreads();
    float* v  = smem;            // 1024
    float* rn = smem + 1024;     // 64
    float* fr = smem + 1088;     // 12
    for (int i = tid; i < 1024; i += 512)
      v[i] = fld(vacc + i) - fld(asum + (i >> 4)) * cent[i];
    __syncthreads();
    if (tid < 64) {
      float ss = 0.f;
      #pragma unroll
      for (int c = 0; c < 16; ++c) { float xx = v[tid * 16 + c]; ss = fmaf(xx, xx, ss); }
      rn[tid] = fmaxf(sqrtf(ss), 1e-12f);
    }
    __syncthreads();
    float gs = 0.f;
    for (int i = tid; i < 1024; i += 512) {
      float nv = v[i] / rn[i >> 4];
      v[i] = nv;
      gs = fmaf(nv, nv, gs);
    }
    #pragma unroll
    for (int o = 32; o > 0; o >>= 1) gs += __shfl_down(gs, o);
    if ((tid & 63) == 0) fr[tid >> 6] = gs;
    __syncthreads();
    if (tid == 0) {
      float tot = 0.f;
      #pragma unroll
      for (int qq = 0; qq < 8; ++qq) tot += fr[qq];
      fr[8] = 1.0f / fmaxf(sqrtf(tot), 1e-12f);
    }
    __syncthreads();
    float invg = fr[8];
    int row = q * 64 + (tid >> 3);
    int cch = tid & 7;
    float acc = 0.f;
    const float4* fw4 = (const float4*)(fcw + row * 1024 + cch * 128);
    const float4* v4  = (const float4*)(v + cch * 128);
    #pragma unroll 4
    for (int i = 0; i < 32; ++i) {
      float4 aa = fw4[i]; float4 xx = v4[i];
      acc = fmaf(aa.x, xx.x, acc); acc = fmaf(aa.y, xx.y, acc);
      acc = fmaf(aa.z, xx.z, acc); acc = fmaf(aa.w, xx.w, acc);
    }
    acc += __shfl_down(acc, 4, 8);
    acc += __shfl_down(acc, 2, 8);
    acc += __shfl_down(acc, 1, 8);
    if (cch == 0) fst(feat + row, fmaf(invg, acc, fcb[row]));
    return;
  }

  // ============================ RNN: bx 41..44 ============================
  if (bx < 45) {
    const int rb_ = bx - 41;               // 0..3
    const int r   = tid >> 2;              // 0..127
    const int cg  = tid & 3;
    const int row = rb_ * 128 + r;
    float wrf[128];
    {
      const float4* wp = (const float4*)(hidw + row * 812 + 300 + cg * 128);
      #pragma unroll
      for (int i = 0; i < 32; ++i) {
        float4 tm = wp[i];
        wrf[4 * i + 0] = tm.x; wrf[4 * i + 1] = tm.y;
        wrf[4 * i + 2] = tm.z; wrf[4 * i + 3] = tm.w;
      }
    }
    float* buf0 = smem;          // 544 floats, swizzled (chunk k at k*136)
    float* buf1 = smem + 544;
    const int wz = (tid >> 7) * 136 + (tid & 127);
    const int wown = ((row >> 7) * 136) + (row & 127);
    const bool own = ((tid >> 7) == rb_);
    unsigned* Hu = (unsigned*)H;
    // ---- stage feat (data-as-flag poll, 1 cell/thread) ----
    {
      const unsigned* fu = (const unsigned*)feat + tid;
      unsigned aa;
      do { aa = uld(fu); } while (aa == POISON);
      buf0[wz] = __uint_as_float(aa);
    }
    unsigned upat = (cg == 0) ? uld((const unsigned*)(U + row)) : 0u;
    __syncthreads();
    for (int t = 0; t < 63; ++t) {
      const float* rbp = ((t & 1) ? buf1 : buf0) + cg * 136;
      float acc = 0.f;
      #pragma unroll
      for (int i = 0; i < 32; ++i) {
        float4 h4 = *(const float4*)(rbp + i * 4);       // wave-broadcast
        acc = fmaf(wrf[4 * i + 0], h4.x, acc);
        acc = fmaf(wrf[4 * i + 1], h4.y, acc);
        acc = fmaf(wrf[4 * i + 2], h4.z, acc);
        acc = fmaf(wrf[4 * i + 3], h4.w, acc);
      }
      acc += __shfl_xor(acc, 1);
      acc += __shfl_xor(acc, 2);
      float hn = 0.f;
      if (cg == 0) {
        while (upat == POISON) upat = uld((const unsigned*)(U + t * 512 + row));
        hn = sigmoidf_(acc + __uint_as_float(upat));
        fst(H + t * 512 + row, hn);
      }
      if (t < 62) {
        float* bufn = (t & 1) ? buf0 : buf1;
        if (cg == 0) {
          bufn[wown] = hn;                 // own row via LDS, no global RT
          upat = uld((const unsigned*)(U + (t + 1) * 512 + row));  // prefetch
        }
        if (!own) {                        // one cell polled per thread
          const unsigned* src = Hu + t * 512 + tid;
          unsigned aa;
          do { aa = uld(src); } while (aa == POISON);
          bufn[wz] = __uint_as_float(aa);
        }
        __syncthreads();                   // single barrier per step
      }
    }
    return;
  }

  // ============================ loss: bx 45..107 ============================
  {
    const int t = bx - 45;
    unsigned* Hu = (unsigned*)H;
    // gate on init (U cells must be poisoned before real values land)
    if (tid == 0) {
      while (uld(flag_magic) != MAGIC) __builtin_amdgcn_s_sleep(8);
    }
    __syncthreads();
    // ---- U[t] = hid_w[:, :300] @ cap0[t] + hid_b ----
    float* csh = smem;                     // 300
    if (tid < 300) csh[tid] = cap[t * 300 + tid];
    __syncthreads();
    {
      float acc = hidb[tid];
      const float4* w4 = (const float4*)(hidw + tid * 812);
      const float4* c4 = (const float4*)csh;
      #pragma unroll 5
      for (int i = 0; i < 75; ++i) {
        float4 aa = w4[i]; float4 xx = c4[i];
        acc = fmaf(aa.x, xx.x, acc); acc = fmaf(aa.y, xx.y, acc);
        acc = fmaf(aa.z, xx.z, acc); acc = fmaf(aa.w, xx.w, acc);
      }
      fst(U + t * 512 + tid, acc);
    }
    __syncthreads();
    // ---- sentinel poll, then full-row poll ----
    if (tid == 0) {
      while (uld(Hu + (size_t)t * 512) == POISON) __builtin_amdgcn_s_sleep(64);
    }
    __syncthreads();
    float* hsh = smem;                     // 512 (csh dead)
    float* red = smem + 512;               // 8
    {
      const unsigned* src = Hu + (size_t)t * 512 + tid;
      unsigned aa;
      do { aa = uld(src); } while (aa == POISON);
      hsh[tid] = __uint_as_float(aa);
    }
    __syncthreads();
    float se = 0.f;
    if (tid < 300) {
      float acc = outb[tid];
      const float4* w4 = (const float4*)(outw + tid * 512);
      const float4* h4 = (const float4*)hsh;
      #pragma unroll 4
      for (int i = 0; i < 128; ++i) {
        float4 aa = w4[i]; float4 xx = h4[i];
        acc = fmaf(aa.x, xx.x, acc); acc = fmaf(aa.y, xx.y, acc);
        acc = fmaf(aa.z, xx.z, acc); acc = fmaf(aa.w, xx.w, acc);
      }
      float y = sigmoidf_(acc);
      float d = y - cap[(t + 1) * 300 + tid];
      se = fmaf(d, d, se);
    }
    #pragma unroll
    for (int o = 32; o > 0; o >>= 1) se += __shfl_down(se, o);
    if ((tid & 63) == 0) red[tid >> 6] = se;
    __syncthreads();
    if (tid == 0) {
      float tot = 0.f;
      #pragma unroll
      for (int qq = 0; qq < 8; ++qq) tot += red[qq];
      atomicAdd(loss, tot * (1.0f / 19200.0f));
    }
  }
}

extern "C" void kernel_launch(void* const* d_in, const int* in_sizes, int n_in,
                              void* d_out, int out_size, void* d_ws, size_t ws_size,
                              hipStream_t stream) {
  (void)in_sizes; (void)n_in; (void)out_size; (void)ws_size;
  const float* img  = (const float*)d_in[0];   // sample 0 only
  const float* cap  = (const float*)d_in[1];   // sample 0 only
  const float* c1w  = (const float*)d_in[2];
  const float* c1b  = (const float*)d_in[3];
  const float* c2w  = (const float*)d_in[4];
  const float* c2b  = (const float*)d_in[5];
  const float* cent = (const float*)d_in[6];
  const float* nvw  = (const float*)d_in[7];
  const float* nvb  = (const float*)d_in[8];
  const float* fcw  = (const float*)d_in[9];
  const float* fcb  = (const float*)d_in[10];
  const float* hidw = (const float*)d_in[11];
  const float* hidb = (const float*)d_in[12];
  const float* outw = (const float*)d_in[13];
  const float* outb = (const float*)d_in[14];

  float* ws   = (float*)d_ws;
  float* vacc = ws;                   // 1024
  float* asum = ws + 1024;            // 64
  float* feat = ws + 1088;            // 512
  float* U    = ws + 1600;            // 63*512 = 32256
  float* H    = ws + 33856;           // 63*512 = 32256
  unsigned* flags = (unsigned*)(ws + 66112);   // [magic, vlad_done]

  k_all<<<108, 512, 0, stream>>>(img, cap, c1w, c1b, c2w, c2b, cent, nvw,
                                 nvb, fcw, fcb, hidw, hidb, outw, outb,
                                 vacc, asum, feat, U, H, flags,
                                 (float*)d_out);
}

// Round 9
// 274.135 us; speedup vs baseline: 1.0922x; 1.0922x over previous
//
#include <hip/hip_runtime.h>
#include <math.h>

// ---------------------------------------------------------------------------
// Only sample 0 of the batch affects the loss (features[0], cap[0]).
// ONE kernel, grid 140 x 512 (all co-resident):
//   bx 0       init: zero vacc/asum/vlad_done/loss; poison U/H/feat (0xAA);
//              __syncthreads drains; release MAGIC.
//   bx 1..4    RNN: 128 rows/block, W_h slice in regs. DATA-AS-FLAG sync;
//              one-time gates (feat, U[0]) use s_sleep backoff so they do
//              NOT hammer the MALL during the front phase (R8's contention);
//              per-step H polls stay tight (latency-critical). Double-
//              buffered swizzled LDS, single barrier per step.
//   bx 5..67   loss t: MAGIC gate; compute U[t] (agent stores); sentinel
//              poll H[t*512] with s_sleep; row poll; y_t; sq-error -> loss.
//   bx 68..131 conv1+conv2+NetVLAD fused, 2 conv2-output rows per block
//              (64 blocks): conv1+pool -> LDS tile (4ch x 6 x 258),
//              conv2+relu+pool, softmax, accumulate (stride-17 reduction
//              scratch: R8's stride-16 was a 16-way bank conflict);
//              MAGIC gate before vacc/asum atomics; tick vlad_done.
//   bx 132..139 FC: wait vlad_done==64; normalize vlad; 64 feat rows each.
// ---------------------------------------------------------------------------

#define POISON 0xAAAAAAAAu
#define MAGIC  0x13579BDFu

__device__ __forceinline__ float sigmoidf_(float x) {
  return 1.0f / (1.0f + __expf(-x));
}
__device__ __forceinline__ unsigned uld(const unsigned* p) {
  return __hip_atomic_load(p, __ATOMIC_RELAXED, __HIP_MEMORY_SCOPE_AGENT);
}
__device__ __forceinline__ float fld(const float* p) {
  return __hip_atomic_load(p, __ATOMIC_RELAXED, __HIP_MEMORY_SCOPE_AGENT);
}
__device__ __forceinline__ void fst(float* p, float v) {
  __hip_atomic_store(p, v, __ATOMIC_RELAXED, __HIP_MEMORY_SCOPE_AGENT);
}
__device__ __forceinline__ void ust(unsigned* p, unsigned v) {
  __hip_atomic_store(p, v, __ATOMIC_RELAXED, __HIP_MEMORY_SCOPE_AGENT);
}

__global__ __launch_bounds__(512, 1)
void k_all(const float* __restrict__ img,  const float* __restrict__ cap,
           const float* __restrict__ c1w,  const float* __restrict__ c1b,
           const float* __restrict__ c2w,  const float* __restrict__ c2b,
           const float* __restrict__ cent, const float* __restrict__ nvw,
           const float* __restrict__ nvb,  const float* __restrict__ fcw,
           const float* __restrict__ fcb,  const float* __restrict__ hidw,
           const float* __restrict__ hidb, const float* __restrict__ outw,
           const float* __restrict__ outb,
           float* __restrict__ vacc, float* __restrict__ asum,
           float* __restrict__ feat, float* __restrict__ U,
           float* __restrict__ H,
           unsigned* __restrict__ flags, float* __restrict__ loss) {
  __shared__ __align__(16) float smem[19520];
  const int bx  = blockIdx.x;
  const int tid = threadIdx.x;
  unsigned* flag_magic = flags + 0;
  unsigned* vlad_done  = flags + 1;

  // ============================ init: bx 0 ============================
  if (bx == 0) {
    for (int i = tid; i < 1024; i += 512) fst(vacc + i, 0.f);
    if (tid < 64) fst(asum + tid, 0.f);
    if (tid == 0) { fst(loss, 0.f); ust(vlad_done, 0u); }
    unsigned* Uu = (unsigned*)U;
    unsigned* Hu = (unsigned*)H;
    unsigned* Fu = (unsigned*)feat;
    for (int i = tid; i < 63 * 512; i += 512) { ust(Uu + i, POISON); ust(Hu + i, POISON); }
    ust(Fu + tid, POISON);
    __syncthreads();                      // drain stores before MAGIC
    if (tid == 0) ust(flag_magic, MAGIC);
    return;
  }

  // ============================ RNN: bx 1..4 ============================
  if (bx < 5) {
    const int rb_ = bx - 1;                // 0..3
    const int r   = tid >> 2;              // 0..127
    const int cg  = tid & 3;
    const int row = rb_ * 128 + r;
    float wrf[128];
    {
      const float4* wp = (const float4*)(hidw + row * 812 + 300 + cg * 128);
      #pragma unroll
      for (int i = 0; i < 32; ++i) {
        float4 tm = wp[i];
        wrf[4 * i + 0] = tm.x; wrf[4 * i + 1] = tm.y;
        wrf[4 * i + 2] = tm.z; wrf[4 * i + 3] = tm.w;
      }
    }
    float* buf0 = smem;          // 544 floats, swizzled (chunk k at k*136)
    float* buf1 = smem + 544;
    const int wz = (tid >> 7) * 136 + (tid & 127);
    const int wown = ((row >> 7) * 136) + (row & 127);
    const bool own = ((tid >> 7) == rb_);
    unsigned* Hu = (unsigned*)H;
    // ---- stage feat: one-time gate, s_sleep backoff (low MALL traffic) ----
    {
      const unsigned* fu = (const unsigned*)feat + tid;
      unsigned aa = uld(fu);
      while (aa == POISON) { __builtin_amdgcn_s_sleep(8); aa = uld(fu); }
      buf0[wz] = __uint_as_float(aa);
    }
    unsigned upat = 0u;
    if (cg == 0) {
      upat = uld((const unsigned*)(U + row));
      while (upat == POISON) {             // one-time; backoff
        __builtin_amdgcn_s_sleep(4);
        upat = uld((const unsigned*)(U + row));
      }
    }
    __syncthreads();
    for (int t = 0; t < 63; ++t) {
      const float* rbp = ((t & 1) ? buf1 : buf0) + cg * 136;
      float acc = 0.f;
      #pragma unroll
      for (int i = 0; i < 32; ++i) {
        float4 h4 = *(const float4*)(rbp + i * 4);       // wave-broadcast
        acc = fmaf(wrf[4 * i + 0], h4.x, acc);
        acc = fmaf(wrf[4 * i + 1], h4.y, acc);
        acc = fmaf(wrf[4 * i + 2], h4.z, acc);
        acc = fmaf(wrf[4 * i + 3], h4.w, acc);
      }
      acc += __shfl_xor(acc, 1);
      acc += __shfl_xor(acc, 2);
      float hn = 0.f;
      if (cg == 0) {
        while (upat == POISON) upat = uld((const unsigned*)(U + t * 512 + row));
        hn = sigmoidf_(acc + __uint_as_float(upat));
        fst(H + t * 512 + row, hn);
      }
      if (t < 62) {
        float* bufn = (t & 1) ? buf0 : buf1;
        if (cg == 0) {
          bufn[wown] = hn;                 // own row via LDS, no global RT
          upat = uld((const unsigned*)(U + (t + 1) * 512 + row));  // prefetch
        }
        if (!own) {                        // one cell polled/thread (tight)
          const unsigned* src = Hu + t * 512 + tid;
          unsigned aa;
          do { aa = uld(src); } while (aa == POISON);
          bufn[wz] = __uint_as_float(aa);
        }
        __syncthreads();                   // single barrier per step
      }
    }
    return;
  }

  // ============================ loss: bx 5..67 ============================
  if (bx < 68) {
    const int t = bx - 5;
    unsigned* Hu = (unsigned*)H;
    if (tid == 0) {                        // U poison must precede our stores
      while (uld(flag_magic) != MAGIC) __builtin_amdgcn_s_sleep(8);
    }
    __syncthreads();
    // ---- U[t] = hid_w[:, :300] @ cap0[t] + hid_b ----
    float* csh = smem;                     // 300
    if (tid < 300) csh[tid] = cap[t * 300 + tid];
    __syncthreads();
    {
      float acc = hidb[tid];
      const float4* w4 = (const float4*)(hidw + tid * 812);
      const float4* c4 = (const float4*)csh;
      #pragma unroll 5
      for (int i = 0; i < 75; ++i) {
        float4 aa = w4[i]; float4 xx = c4[i];
        acc = fmaf(aa.x, xx.x, acc); acc = fmaf(aa.y, xx.y, acc);
        acc = fmaf(aa.z, xx.z, acc); acc = fmaf(aa.w, xx.w, acc);
      }
      fst(U + t * 512 + tid, acc);
    }
    __syncthreads();
    // ---- sentinel poll with backoff, then full-row poll ----
    if (tid == 0) {
      while (uld(Hu + (size_t)t * 512) == POISON) __builtin_amdgcn_s_sleep(64);
    }
    __syncthreads();
    float* hsh = smem;                     // 512 (csh dead)
    float* red = smem + 512;               // 8
    {
      const unsigned* src = Hu + (size_t)t * 512 + tid;
      unsigned aa;
      do { aa = uld(src); } while (aa == POISON);
      hsh[tid] = __uint_as_float(aa);
    }
    __syncthreads();
    float se = 0.f;
    if (tid < 300) {
      float acc = outb[tid];
      const float4* w4 = (const float4*)(outw + tid * 512);
      const float4* h4 = (const float4*)hsh;
      #pragma unroll 4
      for (int i = 0; i < 128; ++i) {
        float4 aa = w4[i]; float4 xx = h4[i];
        acc = fmaf(aa.x, xx.x, acc); acc = fmaf(aa.y, xx.y, acc);
        acc = fmaf(aa.z, xx.z, acc); acc = fmaf(aa.w, xx.w, acc);
      }
      float y = sigmoidf_(acc);
      float d = y - cap[(t + 1) * 300 + tid];
      se = fmaf(d, d, se);
    }
    #pragma unroll
    for (int o = 32; o > 0; o >>= 1) se += __shfl_down(se, o);
    if ((tid & 63) == 0) red[tid >> 6] = se;
    __syncthreads();
    if (tid == 0) {
      float tot = 0.f;
      #pragma unroll
      for (int qq = 0; qq < 8; ++qq) tot += red[qq];
      atomicAdd(loss, tot * (1.0f / 19200.0f));
    }
    return;
  }

  // ==================== conv1+conv2+NetVLAD: bx 68..131 ====================
  if (bx < 132) {
    const int vb = bx - 68;                // 0..63: conv2-out rows [2vb,2vb+1]
    float* p1sh = smem;                    // 4*6*264 = 6336
    float* ps   = smem + 6336;             // 8320 staging; red stride-17 8704
    float* xs   = smem + 14656;            // 2560
    float* wsh  = smem + 17216;            // 1024
    float* bsh  = smem + 18240;            // 64
    float* aS   = smem + 18304;            // 512
    float* cw2  = smem + 18816;            // 576
    float* cb2  = smem + 19392;            // 16
    float* cw1  = smem + 19408;            // 108
    float* cb1  = smem + 19516;            // 4
    for (int i = tid; i < 1024; i += 512) wsh[i] = nvw[i];
    if (tid < 64) bsh[tid] = nvb[tid];
    if (tid < 576) cw2[tid] = c2w[tid];
    if (tid >= 576 && tid < 592) cb2[tid - 576] = c2b[tid - 576];
    if (tid >= 592 && tid < 700) cw1[tid - 592] = c1w[tid - 592];
    if (tid >= 700 && tid < 704) cb1[tid - 700] = c1b[tid - 700];
    __syncthreads();

    // ---- conv1+relu+pool into LDS tile: p1 rows [4vb-1,4vb+4], cols [-1,256]
    for (int f = tid; f < 6192; f += 512) {
      int c  = f / 1548;                   // 1548 = 6*258
      int r0 = f - c * 1548;
      int j  = r0 / 258;
      int xx = r0 - j * 258;
      int gy = 4 * vb - 1 + j;
      int gx = xx - 1;
      float val = 0.f;
      if ((unsigned)gy < 256u && (unsigned)gx < 256u) {
        float bb = cb1[c];
        float a00 = bb, a01 = bb, a10 = bb, a11 = bb;
        int y0 = 2 * gy - 1, x0 = 2 * gx - 1;
        #pragma unroll
        for (int ci = 0; ci < 3; ++ci) {
          float P[4][4];
          #pragma unroll
          for (int jj = 0; jj < 4; ++jj) {
            int y = y0 + jj;
            #pragma unroll
            for (int ii = 0; ii < 4; ++ii) {
              int x = x0 + ii;
              bool ok = ((unsigned)y < 512u) && ((unsigned)x < 512u);
              P[jj][ii] = ok ? img[ci * 262144 + y * 512 + x] : 0.0f;
            }
          }
          #pragma unroll
          for (int ky = 0; ky < 3; ++ky) {
            #pragma unroll
            for (int kx = 0; kx < 3; ++kx) {
              float wv = cw1[c * 27 + ci * 9 + ky * 3 + kx];
              a00 = fmaf(wv, P[ky][kx],         a00);
              a01 = fmaf(wv, P[ky][kx + 1],     a01);
              a10 = fmaf(wv, P[ky + 1][kx],     a10);
              a11 = fmaf(wv, P[ky + 1][kx + 1], a11);
            }
          }
        }
        val = 0.25f * (fmaxf(a00, 0.f) + fmaxf(a01, 0.f) +
                       fmaxf(a10, 0.f) + fmaxf(a11, 0.f));
      }
      p1sh[c * 1584 + j * 264 + xx] = val;
    }
    __syncthreads();

    // ---- conv2+relu+pool: 256 positions (2 rows x 128 cols), tid<256 ----
    float x[16];
    float p[64];
    if (tid < 256) {
      int ox = tid & 127;
      int oyl = tid >> 7;                  // 0..1
      float a[16][4];
      #pragma unroll
      for (int oc = 0; oc < 16; ++oc) {
        float bb = cb2[oc];
        a[oc][0] = bb; a[oc][1] = bb; a[oc][2] = bb; a[oc][3] = bb;
      }
      #pragma unroll
      for (int ci = 0; ci < 4; ++ci) {
        float P[4][4];
        #pragma unroll
        for (int jj = 0; jj < 4; ++jj) {
          #pragma unroll
          for (int ii = 0; ii < 4; ++ii)
            P[jj][ii] = p1sh[ci * 1584 + (2 * oyl + jj) * 264 + 2 * ox + ii];
        }
        #pragma unroll
        for (int oc = 0; oc < 16; ++oc) {
          #pragma unroll
          for (int ky = 0; ky < 3; ++ky) {
            #pragma unroll
            for (int kx = 0; kx < 3; ++kx) {
              float wv = cw2[oc * 36 + ci * 9 + ky * 3 + kx];
              a[oc][0] = fmaf(wv, P[ky][kx],         a[oc][0]);
              a[oc][1] = fmaf(wv, P[ky][kx + 1],     a[oc][1]);
              a[oc][2] = fmaf(wv, P[ky + 1][kx],     a[oc][2]);
              a[oc][3] = fmaf(wv, P[ky + 1][kx + 1], a[oc][3]);
            }
          }
        }
      }
      #pragma unroll
      for (int oc = 0; oc < 16; ++oc)
        x[oc] = 0.25f * (fmaxf(a[oc][0], 0.f) + fmaxf(a[oc][1], 0.f) +
                         fmaxf(a[oc][2], 0.f) + fmaxf(a[oc][3], 0.f));
      // ---- NetVLAD softmax ----
      float m = -1e30f;
      #pragma unroll
      for (int k = 0; k < 64; ++k) {
        float acc = bsh[k];
        #pragma unroll
        for (int c = 0; c < 16; ++c) acc = fmaf(wsh[k * 16 + c], x[c], acc);
        p[k] = acc;
        m = fmaxf(m, acc);
      }
      float s = 0.f;
      #pragma unroll
      for (int k = 0; k < 64; ++k) { p[k] = __expf(p[k] - m); s += p[k]; }
      float inv = 1.0f / s;
      #pragma unroll
      for (int k = 0; k < 64; ++k) p[k] *= inv;
    }

    // ---- accumulate: 2 staging passes of 128 positions ----
    int q = tid >> 6, k = tid & 63;
    float acc[16];
    #pragma unroll
    for (int c = 0; c < 16; ++c) acc[c] = 0.f;
    float accA = 0.f;
    for (int pass = 0; pass < 2; ++pass) {
      __syncthreads();
      if (tid < 256 && (tid >> 7) == pass) {
        int tt = tid & 127;
        #pragma unroll
        for (int kk = 0; kk < 64; ++kk) ps[tt * 65 + kk] = p[kk];
        #pragma unroll
        for (int c = 0; c < 16; ++c) xs[tt * 20 + c] = x[c];
      }
      __syncthreads();
      #pragma unroll
      for (int j = 0; j < 16; ++j) {
        int tt = q * 16 + j;
        float pv = ps[tt * 65 + k];
        accA += pv;
        const float4* xv = (const float4*)(xs + tt * 20);
        #pragma unroll
        for (int c4 = 0; c4 < 4; ++c4) {
          float4 xx = xv[c4];
          acc[c4 * 4 + 0] = fmaf(pv, xx.x, acc[c4 * 4 + 0]);
          acc[c4 * 4 + 1] = fmaf(pv, xx.y, acc[c4 * 4 + 1]);
          acc[c4 * 4 + 2] = fmaf(pv, xx.z, acc[c4 * 4 + 2]);
          acc[c4 * 4 + 3] = fmaf(pv, xx.w, acc[c4 * 4 + 3]);
        }
      }
    }
    __syncthreads();
    float* red = ps;                       // reuse as [512] stride-17
    #pragma unroll
    for (int c = 0; c < 16; ++c) red[tid * 17 + c] = acc[c];
    aS[tid] = accA;
    __syncthreads();
    if (tid == 0) {                        // gate atomics on init done
      while (uld(flag_magic) != MAGIC) __builtin_amdgcn_s_sleep(2);
    }
    __syncthreads();
    if (q == 0) {
      float aa = 0.f;
      #pragma unroll
      for (int qq = 0; qq < 8; ++qq) aa += aS[qq * 64 + k];
      atomicAdd(&asum[k], aa);
    }
    int k2 = tid >> 3;                     // 0..63
    int c0 = (tid & 7) * 2;
    #pragma unroll
    for (int cc = 0; cc < 2; ++cc) {
      int c = c0 + cc;
      float vv = 0.f;
      #pragma unroll
      for (int qq = 0; qq < 8; ++qq) vv += red[(qq * 64 + k2) * 17 + c];
      atomicAdd(&vacc[k2 * 16 + c], vv);
    }
    __syncthreads();                       // drain atomics before tick
    if (tid == 0)
      __hip_atomic_fetch_add(vlad_done, 1u, __ATOMIC_RELAXED,
                             __HIP_MEMORY_SCOPE_AGENT);
    return;
  }

  // ============================ FC: bx 132..139 ============================
  {
    const int q = bx - 132;
    if (tid == 0) {
      while (uld(vlad_done) != 64u) __builtin_amdgcn_s_sleep(8);
    }
    __syncthreads();
    float* v  = smem;            // 1024
    float* rn = smem + 1024;     // 64
    float* fr = smem + 1088;     // 12
    for (int i = tid; i < 1024; i += 512)
      v[i] = fld(vacc + i) - fld(asum + (i >> 4)) * cent[i];
    __syncthreads();
    if (tid < 64) {
      float ss = 0.f;
      #pragma unroll
      for (int c = 0; c < 16; ++c) { float xx = v[tid * 16 + c]; ss = fmaf(xx, xx, ss); }
      rn[tid] = fmaxf(sqrtf(ss), 1e-12f);
    }
    __syncthreads();
    float gs = 0.f;
    for (int i = tid; i < 1024; i += 512) {
      float nv = v[i] / rn[i >> 4];
      v[i] = nv;
      gs = fmaf(nv, nv, gs);
    }
    #pragma unroll
    for (int o = 32; o > 0; o >>= 1) gs += __shfl_down(gs, o);
    if ((tid & 63) == 0) fr[tid >> 6] = gs;
    __syncthreads();
    if (tid == 0) {
      float tot = 0.f;
      #pragma unroll
      for (int qq = 0; qq < 8; ++qq) tot += fr[qq];
      fr[8] = 1.0f / fmaxf(sqrtf(tot), 1e-12f);
    }
    __syncthreads();
    float invg = fr[8];
    int row = q * 64 + (tid >> 3);
    int cch = tid & 7;
    float acc = 0.f;
    const float4* fw4 = (const float4*)(fcw + row * 1024 + cch * 128);
    const float4* v4  = (const float4*)(v + cch * 128);
    #pragma unroll 4
    for (int i = 0; i < 32; ++i) {
      float4 aa = fw4[i]; float4 xx = v4[i];
      acc = fmaf(aa.x, xx.x, acc); acc = fmaf(aa.y, xx.y, acc);
      acc = fmaf(aa.z, xx.z, acc); acc = fmaf(aa.w, xx.w, acc);
    }
    acc += __shfl_down(acc, 4, 8);
    acc += __shfl_down(acc, 2, 8);
    acc += __shfl_down(acc, 1, 8);
    if (cch == 0) fst(feat + row, fmaf(invg, acc, fcb[row]));
  }
}

extern "C" void kernel_launch(void* const* d_in, const int* in_sizes, int n_in,
                              void* d_out, int out_size, void* d_ws, size_t ws_size,
                              hipStream_t stream) {
  (void)in_sizes; (void)n_in; (void)out_size; (void)ws_size;
  const float* img  = (const float*)d_in[0];   // sample 0 only
  const float* cap  = (const float*)d_in[1];   // sample 0 only
  const float* c1w  = (const float*)d_in[2];
  const float* c1b  = (const float*)d_in[3];
  const float* c2w  = (const float*)d_in[4];
  const float* c2b  = (const float*)d_in[5];
  const float* cent = (const float*)d_in[6];
  const float* nvw  = (const float*)d_in[7];
  const float* nvb  = (const float*)d_in[8];
  const float* fcw  = (const float*)d_in[9];
  const float* fcb  = (const float*)d_in[10];
  const float* hidw = (const float*)d_in[11];
  const float* hidb = (const float*)d_in[12];
  const float* outw = (const float*)d_in[13];
  const float* outb = (const float*)d_in[14];

  float* ws   = (float*)d_ws;
  float* vacc = ws;                   // 1024
  float* asum = ws + 1024;            // 64
  float* feat = ws + 1088;            // 512
  float* U    = ws + 1600;            // 63*512 = 32256
  float* H    = ws + 33856;           // 63*512 = 32256
  unsigned* flags = (unsigned*)(ws + 66112);   // [magic, vlad_done]

  k_all<<<140, 512, 0, stream>>>(img, cap, c1w, c1b, c2w, c2b, cent, nvw,
                                 nvb, fcw, fcb, hidw, hidb, outw, outb,
                                 vacc, asum, feat, U, H, flags,
                                 (float*)d_out);
}